// Round 3
// baseline (553.308 us; speedup 1.0000x reference)
//
#include <hip/hip_runtime.h>

typedef unsigned short u16;
typedef unsigned int u32;
typedef __attribute__((ext_vector_type(8))) short short8;
typedef __attribute__((ext_vector_type(4))) float f32x4;
typedef __attribute__((ext_vector_type(2))) unsigned int u32x2;
typedef __attribute__((ext_vector_type(4))) unsigned int u32x4;

#define C_IN 256
#define C_OUT 256
#define VJ 25
#define TT 300
#define VT 7500                          // VJ*TT
#define ROWBLKS 59                       // ceil(7500/128)
#define PERN_ELEMS (ROWBLKS * 4 * 128 * 64)  // 1,933,312 bf16 per n
#define WB_ELEMS (256 * 256)
#define NTOT 32

__device__ __forceinline__ u16 f2bf(float f) {
  u32 u = __float_as_uint(f);
  u32 r = (u + 0x7fffu + ((u >> 16) & 1u)) >> 16;  // RNE, inputs finite
  return (u16)r;
}

// ---------------- K0: W fp32 -> bf16 ----------------
__global__ void k0_wcast(const float* __restrict__ W, u16* __restrict__ Wb) {
  int i = (blockIdx.x * 256 + threadIdx.x) * 4;
  f32x4 w = *(const f32x4*)(W + i);
  u32x2 pk;
  pk[0] = (u32)f2bf(w[0]) | ((u32)f2bf(w[1]) << 16);
  pk[1] = (u32)f2bf(w[2]) | ((u32)f2bf(w[3]) << 16);
  *(u32x2*)(Wb + i) = pk;
}

// ---------------- merged pipelined kernel ----------------
// grid (194, 1, b). bx in [0,76): K1 block (stencil) for n = k1_base + z.
//                   bx in [76,194): K2 block (GEMM) for n = k2_base + z.
// K1 of batch p runs concurrently with K2 of batch p-1 (disjoint ws slots).
__global__ __launch_bounds__(256, 2) void k_pipe(
    const float* __restrict__ x, const float* __restrict__ A,
    const u16* __restrict__ Wb, const float* __restrict__ bias,
    float* __restrict__ out, u16* __restrict__ aggT,
    int k1_base, int k2_base, int nslots) {
  __shared__ __attribute__((aligned(16))) unsigned char smem[58016];
  const int tid = threadIdx.x;
  const int bx = blockIdx.x;
  const int zz = blockIdx.z;

  if (bx < 76) {
    // ================= K1v2: stencil + cast + transpose =================
    // Tile: 16 t x 64 c x all 25 w. Thread = (tq = tid&3, c = tid>>2):
    // owns 4 consecutive t of one channel -> f32x4 loads (25 per thread,
    // 64B contiguous per 4-lane group; was 100 scalar dwords).
    const int n = k1_base + zz;
    if (n >= NTOT) return;
    u16* agg_s = (u16*)smem;                       // [25][16][72] u16
    float(*cw)[4] = (float(*)[4])(smem + 57600);   // [25][4] tridiag coeffs
    const int tblk = bx % 19;                      // 0..18 (t in 16-blocks)
    const int cblk = bx / 19;                      // 0..3  (c in 64-blocks)

    if (tid < 25) {
      int w = tid;
      cw[w][0] = (w > 0) ? A[(w - 1) * 25 + w] : 0.0f;
      cw[w][1] = A[w * 25 + w];
      cw[w][2] = (w < 24) ? A[(w + 1) * 25 + w] : 0.0f;
    }
    __syncthreads();

    const int tq = tid & 3;                        // t-quad [0,4)
    const int c = tid >> 2;                        // local c [0,64)
    const int t0 = tblk * 16 + tq * 4;
    const int tb = (t0 <= TT - 4) ? t0 : (TT - 4); // clamp x4 load; stores masked
    const int cg = cblk * 64 + c;

    const float* xp = x + ((size_t)n * C_IN + cg) * VT + tb;
    f32x4 xv[25];
#pragma unroll
    for (int v = 0; v < 25; ++v) xv[v] = *(const f32x4*)(xp + v * TT);

#pragma unroll
    for (int w = 0; w < 25; ++w) {
      const int wm = (w > 0) ? w - 1 : 0;
      const int wp = (w < 24) ? w + 1 : 24;
      float a0 = cw[w][0], a1 = cw[w][1], a2 = cw[w][2];
#pragma unroll
      for (int i = 0; i < 4; ++i) {
        float r = xv[wm][i] * a0 + xv[w][i] * a1 + xv[wp][i] * a2;
        agg_s[(w * 16 + tq * 4 + i) * 72 + c] = f2bf(r);
      }
    }
    __syncthreads();

    // phase 2: 400 rows (w,t) x 128B, coalesced transposed store
    const int c8 = tid & 7;
    const int rb = tid >> 3;                       // [0,32)
    u16* dstn = aggT + (size_t)(n % nslots) * PERN_ELEMS;
#pragma unroll
    for (int it = 0; it < 13; ++it) {
      int rr = it * 32 + rb;
      if (rr < 400) {
        int w = rr >> 4, ti = rr & 15;
        int t = tblk * 16 + ti;
        if (t < TT) {
          int g = w * TT + t;                      // global row in [0,7500)
          int rowblk = g >> 7, row_in = g & 127;
          u32x4 v = *(const u32x4*)&agg_s[(w * 16 + ti) * 72 + c8 * 8];
          *(u32x4*)(dstn + ((size_t)(rowblk * 4 + cblk) * 128 + row_in) * 64 + c8 * 8) = v;
        }
      }
    }
  } else {
    // ================= K2: bf16 MFMA GEMM + bias =================
    const int n = k2_base + zz;
    if (n < 0 || n >= NTOT) return;
    u16* As = (u16*)smem;                          // [128][64] swizzled
    u16* Bs = (u16*)(smem + 16384);                // [128][64] swizzled
    const int bxx = bx - 76;
    const int cb = bxx % 59;
    const int ob = bxx / 59;
    const int l = tid & 63;
    const int wv = tid >> 6;
    const int wm = wv & 1, wn = wv >> 1;
    const int m = l & 15, quad = l >> 4;
    f32x4 acc[4][4] = {};

    const u16* aggn = aggT + (size_t)(n % nslots) * PERN_ELEMS + (size_t)cb * 4 * 8192;
    const u16* wbase = Wb + ob * 128 * 256;

    for (int kb = 0; kb < 4; ++kb) {
#pragma unroll
      for (int i = 0; i < 4; ++i) {
        int ch = i * 256 + tid;                    // LDS 16B-chunk index
        int row = ch >> 3, jp = ch & 7;
        int jd = jp ^ (row & 7);                   // swizzled-source fetch
        const u16* ga = wbase + row * 256 + kb * 64 + jd * 8;
        __builtin_amdgcn_global_load_lds((const __attribute__((address_space(1))) void*)ga,
                                         (__attribute__((address_space(3))) void*)&As[ch * 8],
                                         16, 0, 0);
        const u16* gb = aggn + kb * 8192 + row * 64 + jd * 8;
        __builtin_amdgcn_global_load_lds((const __attribute__((address_space(1))) void*)gb,
                                         (__attribute__((address_space(3))) void*)&Bs[ch * 8],
                                         16, 0, 0);
      }
      __syncthreads();
#pragma unroll
      for (int ks = 0; ks < 2; ++ks) {
        short8 af[4], bfr[4];
        int jj = ks * 4 + quad;
#pragma unroll
        for (int mi = 0; mi < 4; ++mi) {
          int row = wm * 64 + mi * 16 + m;
          af[mi] = *(const short8*)&As[row * 64 + ((jj ^ (row & 7)) * 8)];
        }
#pragma unroll
        for (int ni = 0; ni < 4; ++ni) {
          int row = wn * 64 + ni * 16 + m;
          bfr[ni] = *(const short8*)&Bs[row * 64 + ((jj ^ (row & 7)) * 8)];
        }
#pragma unroll
        for (int mi = 0; mi < 4; ++mi)
#pragma unroll
          for (int ni = 0; ni < 4; ++ni)
            acc[mi][ni] = __builtin_amdgcn_mfma_f32_16x16x32_bf16(af[mi], bfr[ni], acc[mi][ni], 0, 0, 0);
      }
      __syncthreads();
    }

    // epilogue: C layout col=lane&15, row=quad*4+reg (m89-verified)
    float* outn = out + (size_t)n * C_OUT * VT;
    const int colbase = cb * 128 + wn * 64 + m;
#pragma unroll
    for (int mi = 0; mi < 4; ++mi) {
      const int o0 = ob * 128 + wm * 64 + mi * 16 + quad * 4;
      float b0 = bias[o0], b1 = bias[o0 + 1], b2 = bias[o0 + 2], b3 = bias[o0 + 3];
#pragma unroll
      for (int ni = 0; ni < 4; ++ni) {
        int col = colbase + ni * 16;
        if (col < VT) {
          float* p = outn + (size_t)o0 * VT + col;
          p[0]      = acc[mi][ni][0] + b0;
          p[VT]     = acc[mi][ni][1] + b1;
          p[2 * VT] = acc[mi][ni][2] + b2;
          p[3 * VT] = acc[mi][ni][3] + b3;
        }
      }
    }
  }
}

extern "C" void kernel_launch(void* const* d_in, const int* in_sizes, int n_in,
                              void* d_out, int out_size, void* d_ws, size_t ws_size,
                              hipStream_t stream) {
  (void)in_sizes; (void)n_in; (void)out_size;
  const float* x = (const float*)d_in[0];
  const float* A = (const float*)d_in[1];
  const float* W = (const float*)d_in[2];
  const float* bvec = (const float*)d_in[3];
  float* out = (float*)d_out;
  u16* wb = (u16*)d_ws;                            // [0, 128KB): W in bf16
  u16* aggT = wb + WB_ELEMS;                       // slot-buffered bf16 agg

  const size_t pern_bytes = (size_t)PERN_ELEMS * 2;
  const size_t base_bytes = (size_t)WB_ELEMS * 2;
  int S = 1;                                       // workspace slots
  if (ws_size > base_bytes + pern_bytes) {
    size_t a = (ws_size - base_bytes) / pern_bytes;
    S = (a >= NTOT) ? NTOT : (int)a;
  }

  k0_wcast<<<64, 256, 0, stream>>>(W, wb);

  if (S >= 2) {
    // software-pipelined: launch p runs K1 for [p*b, p*b+b) and K2 for [(p-1)*b, p*b).
    // b = min(4, S/2): 194*b >= 512 blocks keeps 2 blocks/CU x 256 CU filled while
    // minimizing fill/drain ramp (9 launches instead of 3 at b=16). Needs 2b <= S.
    int b = S / 2;
    if (b > 4) b = 4;
    for (int p = 0; (p - 1) * b < NTOT; ++p) {
      k_pipe<<<dim3(194, 1, b), 256, 0, stream>>>(x, A, wb, bvec, out, aggT,
                                                  p * b, (p - 1) * b, S);
    }
  } else {
    // degenerate: strict serial alternation, single slot
    for (int nn = 0; nn < NTOT; ++nn) {
      k_pipe<<<dim3(76, 1, 1), 256, 0, stream>>>(x, A, wb, bvec, out, aggT, nn, -NTOT, 1);
      k_pipe<<<dim3(194, 1, 1), 256, 0, stream>>>(x, A, wb, bvec, out, aggT, NTOT, nn, 1);
    }
  }
}

// Round 8
// 529.269 us; speedup vs baseline: 1.0454x; 1.0454x over previous
//
#include <hip/hip_runtime.h>

typedef unsigned short u16;
typedef unsigned int u32;
typedef __attribute__((ext_vector_type(8))) short short8;
typedef __attribute__((ext_vector_type(4))) float f32x4;
typedef __attribute__((ext_vector_type(2))) unsigned int u32x2;
typedef __attribute__((ext_vector_type(4))) unsigned int u32x4;

#define C_IN 256
#define C_OUT 256
#define VJ 25
#define TT 300
#define VT 7500                          // VJ*TT
#define ROWBLKS 59                       // ceil(7500/128)
#define PERN_ELEMS (ROWBLKS * 4 * 128 * 64)  // 1,933,312 bf16 per n
#define WB_ELEMS (256 * 256)
#define NTOT 32

__device__ __forceinline__ u16 f2bf(float f) {
  u32 u = __float_as_uint(f);
  u32 r = (u + 0x7fffu + ((u >> 16) & 1u)) >> 16;  // RNE, inputs finite
  return (u16)r;
}

// ---------------- K0: W fp32 -> bf16 ----------------
__global__ void k0_wcast(const float* __restrict__ W, u16* __restrict__ Wb) {
  int i = (blockIdx.x * 256 + threadIdx.x) * 4;
  f32x4 w = *(const f32x4*)(W + i);
  u32x2 pk;
  pk[0] = (u32)f2bf(w[0]) | ((u32)f2bf(w[1]) << 16);
  pk[1] = (u32)f2bf(w[2]) | ((u32)f2bf(w[3]) << 16);
  *(u32x2*)(Wb + i) = pk;
}

// ---------------- K1v2: stencil + cast + transpose ----------------
// grid (19 tblk, 4 cblk, nchunk). Thread = (tq=tid&3, c=tid>>2): owns 4
// consecutive t of one channel -> f32x4 loads (25/thread; was 100 scalars).
// Writes aggT[nn][rowblk][kblk=cblk][row_in][c_in] bf16.
__global__ __launch_bounds__(256) void k1_stencil(
    const float* __restrict__ x, const float* __restrict__ A,
    u16* __restrict__ aggT, int n0) {
  __shared__ float cw[25][4];                 // tridiagonal coeffs
  __shared__ u16 agg_s[25 * 16 * 72];         // [w][t 16][c 64 pad->72]
  const int tid = threadIdx.x;
  const int tblk = blockIdx.x;                // 0..18 (t in 16-blocks)
  const int cblk = blockIdx.y;                // 0..3  (c in 64-blocks)
  const int nn = blockIdx.z;
  const int n = n0 + nn;

  if (tid < 25) {
    int w = tid;
    cw[w][0] = (w > 0) ? A[(w - 1) * 25 + w] : 0.0f;
    cw[w][1] = A[w * 25 + w];
    cw[w][2] = (w < 24) ? A[(w + 1) * 25 + w] : 0.0f;
  }
  __syncthreads();

  const int tq = tid & 3;                     // t-quad [0,4)
  const int c = tid >> 2;                     // local c [0,64)
  const int t0 = tblk * 16 + tq * 4;
  const int tb = (t0 <= TT - 4) ? t0 : (TT - 4);  // clamp x4 load; stores masked
  const int cg = cblk * 64 + c;

  const float* xp = x + ((size_t)n * C_IN + cg) * VT + tb;
  f32x4 xv[25];
#pragma unroll
  for (int v = 0; v < 25; ++v) xv[v] = *(const f32x4*)(xp + v * TT);

#pragma unroll
  for (int w = 0; w < 25; ++w) {
    const int wm = (w > 0) ? w - 1 : 0;
    const int wp = (w < 24) ? w + 1 : 24;
    float a0 = cw[w][0], a1 = cw[w][1], a2 = cw[w][2];
#pragma unroll
    for (int i = 0; i < 4; ++i) {
      float r = xv[wm][i] * a0 + xv[w][i] * a1 + xv[wp][i] * a2;
      agg_s[(w * 16 + tq * 4 + i) * 72 + c] = f2bf(r);
    }
  }
  __syncthreads();

  // phase 2: 400 rows (w,t) x 128B, coalesced transposed store
  const int c8 = tid & 7;
  const int rb = tid >> 3;                    // [0,32)
  u16* dstn = aggT + (size_t)nn * PERN_ELEMS;
#pragma unroll
  for (int it = 0; it < 13; ++it) {
    int rr = it * 32 + rb;
    if (rr < 400) {
      int w = rr >> 4, ti = rr & 15;
      int t = tblk * 16 + ti;
      if (t < TT) {
        int g = w * TT + t;                   // global row in [0,7500)
        int rowblk = g >> 7, row_in = g & 127;
        u32x4 v = *(const u32x4*)&agg_s[(w * 16 + ti) * 72 + c8 * 8];
        *(u32x4*)(dstn + ((size_t)(rowblk * 4 + cblk) * 128 + row_in) * 64 + c8 * 8) = v;
      }
    }
  }
}

// ---------------- K2v2: bf16 MFMA GEMM + bias, double-buffered staging ----
// grid (59 colblk, 2 oblk, nchunk). out[n][o][col] = sum_c W[o][c]*agg[col][c] + b[o]
// T3 minimal 2-phase: STAGE(kb+1) issued before compute(kb); __syncthreads'
// implicit vmcnt(0) drain at iteration end guarantees next buffer ready.
__global__ __launch_bounds__(256, 2) void k2_gemm(
    const u16* __restrict__ aggT, const u16* __restrict__ Wb,
    const float* __restrict__ bias, float* __restrict__ out, int n0) {
  __shared__ u16 As[2][128 * 64];             // [buf][o-row][64k], XOR-swizzled
  __shared__ u16 Bs[2][128 * 64];             // [buf][col-row][64k], same swizzle
  const int tid = threadIdx.x;
  const int cb = blockIdx.x;
  const int ob = blockIdx.y;
  const int nn = blockIdx.z;
  const int n = n0 + nn;
  const int l = tid & 63;
  const int wv = tid >> 6;
  const int wm = wv & 1, wn = wv >> 1;
  const int m = l & 15, quad = l >> 4;
  f32x4 acc[4][4] = {};

  const u16* aggn = aggT + (size_t)nn * PERN_ELEMS + (size_t)cb * 4 * 8192;
  const u16* wbase = Wb + ob * 128 * 256;

  // per-thread staging geometry (loop-invariant)
  const int ch0 = tid;                        // chunk ids: tid + {0,256,512,768}
#define STAGE_KB(kb, pb)                                                        \
  {                                                                             \
    _Pragma("unroll")                                                           \
    for (int i = 0; i < 4; ++i) {                                               \
      int ch = i * 256 + ch0;                                                   \
      int row = ch >> 3, jp = ch & 7;                                           \
      int jd = jp ^ (row & 7);                                                  \
      const u16* ga = wbase + row * 256 + (kb) * 64 + jd * 8;                   \
      __builtin_amdgcn_global_load_lds(                                         \
          (const __attribute__((address_space(1))) void*)ga,                    \
          (__attribute__((address_space(3))) void*)&As[pb][ch * 8], 16, 0, 0);  \
      const u16* gb = aggn + (kb) * 8192 + row * 64 + jd * 8;                   \
      __builtin_amdgcn_global_load_lds(                                         \
          (const __attribute__((address_space(1))) void*)gb,                    \
          (__attribute__((address_space(3))) void*)&Bs[pb][ch * 8], 16, 0, 0);  \
    }                                                                           \
  }

  STAGE_KB(0, 0);
  __syncthreads();                            // vmcnt(0) drain + barrier: buf0 ready

  for (int kb = 0; kb < 4; ++kb) {
    const int cur = kb & 1;
    if (kb < 3) STAGE_KB(kb + 1, cur ^ 1);    // flies during compute below
#pragma unroll
    for (int ks = 0; ks < 2; ++ks) {
      short8 af[4], bfr[4];
      int jj = ks * 4 + quad;
#pragma unroll
      for (int mi = 0; mi < 4; ++mi) {
        int row = wm * 64 + mi * 16 + m;
        af[mi] = *(const short8*)&As[cur][row * 64 + ((jj ^ (row & 7)) * 8)];
      }
#pragma unroll
      for (int ni = 0; ni < 4; ++ni) {
        int row = wn * 64 + ni * 16 + m;
        bfr[ni] = *(const short8*)&Bs[cur][row * 64 + ((jj ^ (row & 7)) * 8)];
      }
#pragma unroll
      for (int mi = 0; mi < 4; ++mi)
#pragma unroll
        for (int ni = 0; ni < 4; ++ni)
          acc[mi][ni] = __builtin_amdgcn_mfma_f32_16x16x32_bf16(af[mi], bfr[ni], acc[mi][ni], 0, 0, 0);
    }
    __syncthreads();                          // drains STAGE(kb+1); next buf ready
  }
#undef STAGE_KB

  // epilogue: C layout col=lane&15, row=quad*4+reg (m89-verified)
  float* outn = out + (size_t)n * C_OUT * VT;
  const int colbase = cb * 128 + wn * 64 + m;
#pragma unroll
  for (int mi = 0; mi < 4; ++mi) {
    const int o0 = ob * 128 + wm * 64 + mi * 16 + quad * 4;
    float b0 = bias[o0], b1 = bias[o0 + 1], b2 = bias[o0 + 2], b3 = bias[o0 + 3];
#pragma unroll
    for (int ni = 0; ni < 4; ++ni) {
      int col = colbase + ni * 16;
      if (col < VT) {
        float* p = outn + (size_t)o0 * VT + col;
        p[0]      = acc[mi][ni][0] + b0;
        p[VT]     = acc[mi][ni][1] + b1;
        p[2 * VT] = acc[mi][ni][2] + b2;
        p[3 * VT] = acc[mi][ni][3] + b3;
      }
    }
  }
}

extern "C" void kernel_launch(void* const* d_in, const int* in_sizes, int n_in,
                              void* d_out, int out_size, void* d_ws, size_t ws_size,
                              hipStream_t stream) {
  (void)in_sizes; (void)n_in; (void)out_size;
  const float* x = (const float*)d_in[0];
  const float* A = (const float*)d_in[1];
  const float* W = (const float*)d_in[2];
  const float* b = (const float*)d_in[3];
  float* out = (float*)d_out;
  u16* wb = (u16*)d_ws;                       // [0, 128KB): W in bf16
  u16* aggT = wb + WB_ELEMS;                  // transposed bf16 agg, chunked over n

  const size_t pern_bytes = (size_t)PERN_ELEMS * 2;
  const size_t base_bytes = (size_t)WB_ELEMS * 2;
  int nchunk = 1;                             // full run needs ~118 MiB of ws
  if (ws_size > base_bytes + pern_bytes) {
    size_t a = (ws_size - base_bytes) / pern_bytes;
    nchunk = (a >= NTOT) ? NTOT : (int)a;
  }

  k0_wcast<<<64, 256, 0, stream>>>(W, wb);
  for (int n0 = 0; n0 < NTOT; n0 += nchunk) {
    int nc = NTOT - n0; if (nc > nchunk) nc = nchunk;
    k1_stencil<<<dim3(19, 4, nc), 256, 0, stream>>>(x, A, aggT, n0);
    k2_gemm<<<dim3(59, 2, nc), 256, 0, stream>>>(aggT, wb, b, out, n0);
  }
}